// Round 3
// baseline (192.154 us; speedup 1.0000x reference)
//
#include <hip/hip_runtime.h>
#include <hip/hip_bf16.h>
#include <math.h>

#define N_POINTS 32
#define SPACE_DIM 16
#define EMB 512
#define THRESH 0.1f
#define MAX_ITER 10

// log2-domain constants
#define NEG10LOG2E -14.42695040888963f   // -10*log2(e): C -> Crow2
#define EPS_LN2     0.0693147180559945f  // eps*ln2: U2-delta -> u-delta, Crow2 -> -C
#define LOGMU2     -4.99999953834f       // log2(1/32 + 1e-8)

// ---------------- GEMM: Z = X @ W  (fp32, A in LDS double-buffered, B from global)
#define BM 64
#define BN 64
#define BK 16
#define LDP 68

__global__ __launch_bounds__(256) void gemm_f32(
    const float* __restrict__ X, const float* __restrict__ W,
    float* __restrict__ Z, int M, int K, int N)
{
    __shared__ float As[2][BK][LDP];   // [buf][k][m]

    int m0 = blockIdx.x * BM, n0 = blockIdx.y * BN;
    int t = threadIdx.x;
    int tx = t & 15, ty = t >> 4;      // 16x16 threads, each 4x4 output

    int arow = t >> 2;                 // 0..63  (m within tile)
    int akc  = (t & 3) * 4;            // 0,4,8,12 (k within tile)

    int gm = m0 + arow;
    const float* xrow = X + (size_t)gm * K;
    const float* wcol = W + n0 + tx * 4;

    float acc[4][4] = {};

    // preload tile 0
    {
        float4 va = make_float4(0.f, 0.f, 0.f, 0.f);
        if (gm < M) va = *(const float4*)&xrow[akc];
        As[0][akc + 0][arow] = va.x;
        As[0][akc + 1][arow] = va.y;
        As[0][akc + 2][arow] = va.z;
        As[0][akc + 3][arow] = va.w;
    }
    __syncthreads();

    int p = 0;
    for (int k0 = 0; k0 < K; k0 += BK) {
        // prefetch next A tile into the other buffer (no one reads it yet)
        if (k0 + BK < K) {
            float4 va = make_float4(0.f, 0.f, 0.f, 0.f);
            if (gm < M) va = *(const float4*)&xrow[k0 + BK + akc];
            As[p ^ 1][akc + 0][arow] = va.x;
            As[p ^ 1][akc + 1][arow] = va.y;
            As[p ^ 1][akc + 2][arow] = va.z;
            As[p ^ 1][akc + 3][arow] = va.w;
        }
        // compute on current buffer; B straight from global (L1 broadcast)
        #pragma unroll
        for (int kk = 0; kk < BK; ++kk) {
            float4 a = *(const float4*)&As[p][kk][ty * 4];
            float4 b = *(const float4*)&wcol[(size_t)(k0 + kk) * N];
            float av[4] = {a.x, a.y, a.z, a.w};
            float bv[4] = {b.x, b.y, b.z, b.w};
            #pragma unroll
            for (int i = 0; i < 4; ++i)
                #pragma unroll
                for (int j = 0; j < 4; ++j)
                    acc[i][j] = fmaf(av[i], bv[j], acc[i][j]);
        }
        __syncthreads();
        p ^= 1;
    }
    #pragma unroll
    for (int i = 0; i < 4; ++i) {
        int gmo = m0 + ty * 4 + i;
        if (gmo < M) {
            *(float4*)&Z[(size_t)gmo * N + n0 + tx * 4] =
                make_float4(acc[i][0], acc[i][1], acc[i][2], acc[i][3]);
        }
    }
}

// ---------------- Fused Sinkhorn: 4 edges/block, 1 wave/edge, log2 domain ---
// Per-wave LDS slices; NO barriers (wave-internal DS ordering suffices).
// Crow2 = -10*log2e*C ; U2 = u/(eps*ln2) ; V2 likewise.
// Row pass: U2n = LOGMU2 - l2se_j(Crow2 + V2_j); cost fused into same exps.
#define WPB 4

__global__ __launch_bounds__(256) void sinkhorn_fused(
    const float* __restrict__ Z,
    const int* __restrict__ ep, const int* __restrict__ en,
    int nE,
    float* __restrict__ err_part,   // [MAX_ITER][2nE]
    float* __restrict__ cost_all)   // [MAX_ITER][2nE]
{
    __shared__ float shm[WPB][32 * 36];  // union: sb = 32x20, csh = 32x36
    __shared__ float uvs[WPB][64];       // U2[0:32], V2[32:64]

    int tid = threadIdx.x;
    int wv = tid >> 6;
    int t = tid & 63;
    int b = blockIdx.x * WPB + wv;
    if (b >= 2 * nE) return;

    int side = (b >= nE) ? 1 : 0;
    int e = b - side * nE;
    const int* edges = side ? en : ep;
    int nx = edges[e];
    int ny = edges[e + nE];

    int c = t & 31;          // row (row pass) / col (col pass)
    int h = t >> 5;
    int r0 = h * 16;

    float* sb  = shm[wv];
    float* csh = shm[wv];
    float* Ul  = uvs[wv];
    float* Vl  = uvs[wv] + 32;

    // stage b point rows into LDS, padded stride 20
    {
        const float4* zb4 = (const float4*)(Z + (size_t)ny * EMB);
        float4 q0 = zb4[t * 2];
        float4 q1 = zb4[t * 2 + 1];
        float* dst = sb + (t >> 1) * 20 + (t & 1) * 8;
        ((float4*)dst)[0] = q0;
        ((float4*)dst)[1] = q1;
    }
    // own a-row in registers
    float areg[16];
    {
        const float4* za4 = (const float4*)(Z + (size_t)nx * EMB + c * SPACE_DIM);
        float4 a0 = za4[0], a1 = za4[1], a2 = za4[2], a3 = za4[3];
        areg[0]=a0.x; areg[1]=a0.y; areg[2]=a0.z; areg[3]=a0.w;
        areg[4]=a1.x; areg[5]=a1.y; areg[6]=a1.z; areg[7]=a1.w;
        areg[8]=a2.x; areg[9]=a2.y; areg[10]=a2.z; areg[11]=a2.w;
        areg[12]=a3.x; areg[13]=a3.y; areg[14]=a3.z; areg[15]=a3.w;
    }

    // Crow2[jj] = -10*log2e * ||a_c - b_{r0+jj}||^2   (broadcast LDS reads)
    float Crow[16];
    #pragma unroll
    for (int jj = 0; jj < 16; ++jj) {
        const float* bp = sb + (r0 + jj) * 20;
        float s = 0.f;
        #pragma unroll
        for (int d = 0; d < SPACE_DIM; ++d) {
            float diff = areg[d] - bp[d];
            s = fmaf(diff, diff, s);
        }
        Crow[jj] = s * NEG10LOG2E;
    }
    // transpose through LDS (stride 36, b128-aligned) to get column fragment.
    // All sb reads above are issued before these writes (in-order wave).
    #pragma unroll
    for (int g = 0; g < 4; ++g) {
        *(float4*)&csh[c * 36 + r0 + g * 4] =
            make_float4(Crow[g*4+0], Crow[g*4+1], Crow[g*4+2], Crow[g*4+3]);
    }
    float Ccol[16];
    #pragma unroll
    for (int ii = 0; ii < 16; ++ii)
        Ccol[ii] = csh[(r0 + ii) * 36 + c];

    Vl[c] = 0.f;   // duplicate write across halves: same addr, same value
    float U = 0.f;

    for (int it = 0; it < MAX_ITER; ++it) {
        // ---- row pass ----
        float w[16];
        {
            const float4* vp = (const float4*)(Vl + r0);
            float4 v0 = vp[0], v1 = vp[1], v2 = vp[2], v3 = vp[3];
            float vv[16] = {v0.x,v0.y,v0.z,v0.w, v1.x,v1.y,v1.z,v1.w,
                            v2.x,v2.y,v2.z,v2.w, v3.x,v3.y,v3.z,v3.w};
            #pragma unroll
            for (int jj = 0; jj < 16; ++jj) w[jj] = Crow[jj] + vv[jj];
        }
        float mx = w[0];
        #pragma unroll
        for (int jj = 1; jj < 16; ++jj) mx = fmaxf(mx, w[jj]);
        mx = fmaxf(mx, __shfl_xor(mx, 32));
        float sm = 0.f, pc = 0.f;
        #pragma unroll
        for (int jj = 0; jj < 16; ++jj) {
            float ex = exp2f(w[jj] - mx);
            sm += ex;
            pc = fmaf(ex, Crow[jj], pc);   // cost partial, reuses the exps
        }
        sm += __shfl_xor(sm, 32);

        // cost of state after `it` iterations (pre-update U; V just read)
        if (it > 0) {
            float cc = exp2f(U + mx) * pc;   // per-lane half-row contribution
            #pragma unroll
            for (int m = 1; m < 64; m <<= 1) cc += __shfl_xor(cc, m);
            if (t == 0)
                cost_all[(size_t)(it - 1) * (2 * nE) + b] = -EPS_LN2 * cc;
        }

        float Un = LOGMU2 - (mx + log2f(sm));
        float du = (h == 0) ? fabsf(Un - U) : 0.f;
        #pragma unroll
        for (int m = 1; m < 64; m <<= 1) du += __shfl_xor(du, m);
        if (t == 0) err_part[(size_t)it * (2 * nE) + b] = EPS_LN2 * du;
        U = Un;
        Ul[c] = U;   // duplicate write, same value

        // ---- col pass ----
        float wc[16];
        {
            const float4* up = (const float4*)(Ul + r0);
            float4 u0 = up[0], u1 = up[1], u2 = up[2], u3 = up[3];
            float uu[16] = {u0.x,u0.y,u0.z,u0.w, u1.x,u1.y,u1.z,u1.w,
                            u2.x,u2.y,u2.z,u2.w, u3.x,u3.y,u3.z,u3.w};
            #pragma unroll
            for (int ii = 0; ii < 16; ++ii) wc[ii] = Ccol[ii] + uu[ii];
        }
        float mx2 = wc[0];
        #pragma unroll
        for (int ii = 1; ii < 16; ++ii) mx2 = fmaxf(mx2, wc[ii]);
        mx2 = fmaxf(mx2, __shfl_xor(mx2, 32));
        float sm2 = 0.f;
        #pragma unroll
        for (int ii = 0; ii < 16; ++ii) sm2 += exp2f(wc[ii] - mx2);
        sm2 += __shfl_xor(sm2, 32);
        float Vn = LOGMU2 - (mx2 + log2f(sm2));
        Vl[c] = Vn;  // duplicate write, same value
    }

    // cost of final state (after MAX_ITER iterations) -> index MAX_ITER-1
    {
        const float4* vp = (const float4*)(Vl + r0);
        float4 v0 = vp[0], v1 = vp[1], v2 = vp[2], v3 = vp[3];
        float vv[16] = {v0.x,v0.y,v0.z,v0.w, v1.x,v1.y,v1.z,v1.w,
                        v2.x,v2.y,v2.z,v2.w, v3.x,v3.y,v3.z,v3.w};
        float cc = 0.f;
        #pragma unroll
        for (int jj = 0; jj < 16; ++jj)
            cc = fmaf(exp2f(U + Crow[jj] + vv[jj]), Crow[jj], cc);
        #pragma unroll
        for (int m = 1; m < 64; m <<= 1) cc += __shfl_xor(cc, m);
        if (t == 0)
            cost_all[(size_t)(MAX_ITER - 1) * (2 * nE) + b] = -EPS_LN2 * cc;
    }
}

// ---------------- err reduction: 20 blocks, deterministic ----------------
__global__ __launch_bounds__(256) void err_reduce(
    const float* __restrict__ err_part, float* __restrict__ err_mean, int nE)
{
    int side = blockIdx.x / MAX_ITER;
    int it = blockIdx.x - side * MAX_ITER;
    const float* p = err_part + (size_t)it * (2 * nE) + side * nE;
    float s = 0.f;
    for (int idx = threadIdx.x; idx < nE; idx += 256) s += p[idx];
    __shared__ float red[256];
    red[threadIdx.x] = s;
    __syncthreads();
    for (int stride = 128; stride > 0; stride >>= 1) {
        if (threadIdx.x < stride) red[threadIdx.x] += red[threadIdx.x + stride];
        __syncthreads();
    }
    if (threadIdx.x == 0) err_mean[side * MAX_ITER + it] = red[0] / (float)nE;
}

// ---------------- final: pick T per side, gather costs, reduce loss -------
__global__ __launch_bounds__(256) void final_loss(
    const float* __restrict__ err_mean, const float* __restrict__ cost_all,
    float* __restrict__ out, int nE)
{
    int Tp = MAX_ITER, Tn = MAX_ITER;
    for (int it = 0; it < MAX_ITER; ++it)
        if (err_mean[it] < THRESH) { Tp = it + 1; break; }
    for (int it = 0; it < MAX_ITER; ++it)
        if (err_mean[MAX_ITER + it] < THRESH) { Tn = it + 1; break; }

    float s = 0.f;
    for (int b = threadIdx.x; b < 2 * nE; b += 256) {
        int side = (b >= nE) ? 1 : 0;
        int T = side ? Tn : Tp;
        float cost = cost_all[(size_t)(T - 1) * (2 * nE) + b];
        s += side ? expf(-cost) : cost * cost;
    }
    __shared__ float red[256];
    red[threadIdx.x] = s;
    __syncthreads();
    for (int stride = 128; stride > 0; stride >>= 1) {
        if (threadIdx.x < stride) red[threadIdx.x] += red[threadIdx.x + stride];
        __syncthreads();
    }
    if (threadIdx.x == 0) out[0] = red[0] / (float)nE;
}

extern "C" void kernel_launch(void* const* d_in, const int* in_sizes, int n_in,
                              void* d_out, int out_size, void* d_ws, size_t ws_size,
                              hipStream_t stream)
{
    const float* X = (const float*)d_in[0];
    const float* W = (const float*)d_in[1];
    const int* ep = (const int*)d_in[2];
    const int* en = (const int*)d_in[3];
    float* out = (float*)d_out;

    int K = in_sizes[1] / EMB;     // 256
    int M = in_sizes[0] / K;       // 10000
    int nE = in_sizes[2] / 2;      // 4096

    float* ws = (float*)d_ws;
    float* Z = ws;                                              // M*EMB
    float* err_part = Z + (size_t)M * EMB;                      // MAX_ITER*2nE
    float* cost_all = err_part + (size_t)MAX_ITER * 2 * nE;     // MAX_ITER*2nE
    float* err_mean = cost_all + (size_t)MAX_ITER * 2 * nE;     // 32 (20 used)

    dim3 gg((M + BM - 1) / BM, EMB / BN);
    gemm_f32<<<gg, 256, 0, stream>>>(X, W, Z, M, K, EMB);

    int nblk = (2 * nE + WPB - 1) / WPB;
    sinkhorn_fused<<<nblk, 64 * WPB, 0, stream>>>(Z, ep, en, nE, err_part, cost_all);
    err_reduce<<<2 * MAX_ITER, 256, 0, stream>>>(err_part, err_mean, nE);
    final_loss<<<1, 256, 0, stream>>>(err_mean, cost_all, out, nE);
}

// Round 4
// 159.655 us; speedup vs baseline: 1.2036x; 1.2036x over previous
//
#include <hip/hip_runtime.h>
#include <hip/hip_bf16.h>
#include <math.h>

#define N_POINTS 32
#define SPACE_DIM 16
#define EMB 512
#define THRESH 0.1f
#define MAX_ITER 10

// log2-domain constants
#define NEG10LOG2E -14.42695040888963f   // -10*log2(e): C -> Crow2
#define EPS_LN2     0.0693147180559945f  // eps*ln2
#define LOGMU2     -4.99999953834f       // log2(1/32 + 1e-8)

typedef _Float16 half8 __attribute__((ext_vector_type(8)));
typedef float floatx4 __attribute__((ext_vector_type(4)));

// ---------------- convert: X -> f16 flat, W -> f16 transposed ----------------
__global__ __launch_bounds__(256) void convert_f16(
    const float* __restrict__ X, const float* __restrict__ W,
    _Float16* __restrict__ Xh, _Float16* __restrict__ WhT,
    int MK, int K, int N, int total)
{
    int idx = blockIdx.x * 256 + threadIdx.x;
    if (idx < MK) {
        Xh[idx] = (_Float16)X[idx];
    } else if (idx < total) {
        int f = idx - MK;
        int n = f / K;
        int k = f - n * K;
        WhT[f] = (_Float16)W[(size_t)k * N + n];   // WhT[n][k]
    }
}

// ---------------- MFMA GEMM: Z = Xh @ WhT^T, fp32 out, LDS-free -------------
// wave = 16 rows x 64 cols; block = 4 waves = 64x64 tile.
// A-frag: lane holds A[m=lane&15][k=quad*8+j]  (16B contiguous in Xh)
// B-frag: lane holds B[k=quad*8+j][n=lane&15]  (16B contiguous in WhT)
// C/D:    lane reg r -> D[row=quad*4+r][col=lane&15]
__global__ __launch_bounds__(256) void gemm_mfma_f16(
    const _Float16* __restrict__ Xh, const _Float16* __restrict__ WhT,
    float* __restrict__ Z, int M, int K, int N)
{
    int t = threadIdx.x;
    int wave = t >> 6;
    int lane = t & 63;
    int quad = lane >> 4;
    int l16 = lane & 15;

    int mrow = blockIdx.x * 64 + wave * 16 + l16;
    int msafe = mrow < M ? mrow : M - 1;
    int n0 = blockIdx.y * 64;

    const _Float16* arow  = Xh + (size_t)msafe * K + quad * 8;
    const _Float16* bcol0 = WhT + (size_t)(n0 + l16) * K + quad * 8;

    floatx4 acc[4] = {{0.f,0.f,0.f,0.f},{0.f,0.f,0.f,0.f},
                      {0.f,0.f,0.f,0.f},{0.f,0.f,0.f,0.f}};

    for (int k0 = 0; k0 < K; k0 += 32) {
        half8 a = *(const half8*)(arow + k0);
        #pragma unroll
        for (int ct = 0; ct < 4; ++ct) {
            half8 b = *(const half8*)(bcol0 + (size_t)ct * 16 * K + k0);
            acc[ct] = __builtin_amdgcn_mfma_f32_16x16x32_f16(a, b, acc[ct], 0, 0, 0);
        }
    }

    int rbase = blockIdx.x * 64 + wave * 16 + quad * 4;
    #pragma unroll
    for (int ct = 0; ct < 4; ++ct) {
        int col = n0 + ct * 16 + l16;
        #pragma unroll
        for (int r = 0; r < 4; ++r) {
            int row = rbase + r;
            if (row < M) Z[(size_t)row * N + col] = acc[ct][r];
        }
    }
}

// ---------------- Fused Sinkhorn: 4 edges/block, 1 wave/edge, log2 domain ---
#define WPB 4

__global__ __launch_bounds__(256, 4) void sinkhorn_fused(
    const float* __restrict__ Z,
    const int* __restrict__ ep, const int* __restrict__ en,
    int nE,
    float* __restrict__ err_part,   // [MAX_ITER][2nE]
    float* __restrict__ cost_all)   // [MAX_ITER][2nE]
{
    __shared__ float shm[WPB][32 * 36];  // union: sb = 32x20, csh = 32x36
    __shared__ float uvs[WPB][64];       // U2[0:32], V2[32:64]

    int tid = threadIdx.x;
    int wv = tid >> 6;
    int t = tid & 63;
    int b = blockIdx.x * WPB + wv;

    int side = (b >= nE) ? 1 : 0;
    int e = b - side * nE;
    const int* edges = side ? en : ep;
    int nx = edges[e];
    int ny = edges[e + nE];

    int c = t & 31;
    int h = t >> 5;
    int r0 = h * 16;

    float* sb  = shm[wv];
    float* csh = shm[wv];
    float* Ul  = uvs[wv];
    float* Vl  = uvs[wv] + 32;

    // stage b point rows into LDS, padded stride 20
    {
        const float4* zb4 = (const float4*)(Z + (size_t)ny * EMB);
        float4 q0 = zb4[t * 2];
        float4 q1 = zb4[t * 2 + 1];
        float* dst = sb + (t >> 1) * 20 + (t & 1) * 8;
        ((float4*)dst)[0] = q0;
        ((float4*)dst)[1] = q1;
    }
    // own a-row in registers
    float areg[16];
    {
        const float4* za4 = (const float4*)(Z + (size_t)nx * EMB + c * SPACE_DIM);
        float4 a0 = za4[0], a1 = za4[1], a2 = za4[2], a3 = za4[3];
        areg[0]=a0.x; areg[1]=a0.y; areg[2]=a0.z; areg[3]=a0.w;
        areg[4]=a1.x; areg[5]=a1.y; areg[6]=a1.z; areg[7]=a1.w;
        areg[8]=a2.x; areg[9]=a2.y; areg[10]=a2.z; areg[11]=a2.w;
        areg[12]=a3.x; areg[13]=a3.y; areg[14]=a3.z; areg[15]=a3.w;
    }

    // Crow[jj] = -10*log2e * ||a_c - b_{r0+jj}||^2
    float Crow[16];
    #pragma unroll
    for (int jj = 0; jj < 16; ++jj) {
        const float* bp = sb + (r0 + jj) * 20;
        float s = 0.f;
        #pragma unroll
        for (int d = 0; d < SPACE_DIM; ++d) {
            float diff = areg[d] - bp[d];
            s = fmaf(diff, diff, s);
        }
        Crow[jj] = s * NEG10LOG2E;
    }
    // transpose through LDS (stride 36) to get column fragment
    #pragma unroll
    for (int g = 0; g < 4; ++g) {
        *(float4*)&csh[c * 36 + r0 + g * 4] =
            make_float4(Crow[g*4+0], Crow[g*4+1], Crow[g*4+2], Crow[g*4+3]);
    }
    float Ccol[16];
    #pragma unroll
    for (int ii = 0; ii < 16; ++ii)
        Ccol[ii] = csh[(r0 + ii) * 36 + c];

    Vl[c] = 0.f;
    float U = 0.f;

    for (int it = 0; it < MAX_ITER; ++it) {
        // ---- row pass ----
        float w[16];
        {
            const float4* vp = (const float4*)(Vl + r0);
            float4 v0 = vp[0], v1 = vp[1], v2 = vp[2], v3 = vp[3];
            float vv[16] = {v0.x,v0.y,v0.z,v0.w, v1.x,v1.y,v1.z,v1.w,
                            v2.x,v2.y,v2.z,v2.w, v3.x,v3.y,v3.z,v3.w};
            #pragma unroll
            for (int jj = 0; jj < 16; ++jj) w[jj] = Crow[jj] + vv[jj];
        }
        float mx = w[0];
        #pragma unroll
        for (int jj = 1; jj < 16; ++jj) mx = fmaxf(mx, w[jj]);
        mx = fmaxf(mx, __shfl_xor(mx, 32));
        float sm = 0.f, pc = 0.f;
        #pragma unroll
        for (int jj = 0; jj < 16; ++jj) {
            float ex = __builtin_amdgcn_exp2f(w[jj] - mx);
            sm += ex;
            pc = fmaf(ex, Crow[jj], pc);   // cost partial reusing the exps
        }
        sm += __shfl_xor(sm, 32);

        if (it > 0) {
            float cc = __builtin_amdgcn_exp2f(U + mx) * pc;
            #pragma unroll
            for (int m = 1; m < 64; m <<= 1) cc += __shfl_xor(cc, m);
            if (t == 0)
                cost_all[(size_t)(it - 1) * (2 * nE) + b] = -EPS_LN2 * cc;
        }

        float Un = LOGMU2 - (mx + __builtin_amdgcn_logf(sm));
        // du identical across halves -> 5-level tree over lanes 0..31
        float du = fabsf(Un - U);
        #pragma unroll
        for (int m = 1; m < 32; m <<= 1) du += __shfl_xor(du, m);
        if (t == 0) err_part[(size_t)it * (2 * nE) + b] = EPS_LN2 * du;
        U = Un;
        Ul[c] = U;

        // ---- col pass ----
        float wc[16];
        {
            const float4* up = (const float4*)(Ul + r0);
            float4 u0 = up[0], u1 = up[1], u2 = up[2], u3 = up[3];
            float uu[16] = {u0.x,u0.y,u0.z,u0.w, u1.x,u1.y,u1.z,u1.w,
                            u2.x,u2.y,u2.z,u2.w, u3.x,u3.y,u3.z,u3.w};
            #pragma unroll
            for (int ii = 0; ii < 16; ++ii) wc[ii] = Ccol[ii] + uu[ii];
        }
        float mx2 = wc[0];
        #pragma unroll
        for (int ii = 1; ii < 16; ++ii) mx2 = fmaxf(mx2, wc[ii]);
        mx2 = fmaxf(mx2, __shfl_xor(mx2, 32));
        float sm2 = 0.f;
        #pragma unroll
        for (int ii = 0; ii < 16; ++ii) sm2 += __builtin_amdgcn_exp2f(wc[ii] - mx2);
        sm2 += __shfl_xor(sm2, 32);
        float Vn = LOGMU2 - (mx2 + __builtin_amdgcn_logf(sm2));
        Vl[c] = Vn;
    }

    // final-state cost -> index MAX_ITER-1
    {
        const float4* vp = (const float4*)(Vl + r0);
        float4 v0 = vp[0], v1 = vp[1], v2 = vp[2], v3 = vp[3];
        float vv[16] = {v0.x,v0.y,v0.z,v0.w, v1.x,v1.y,v1.z,v1.w,
                        v2.x,v2.y,v2.z,v2.w, v3.x,v3.y,v3.z,v3.w};
        float cc = 0.f;
        #pragma unroll
        for (int jj = 0; jj < 16; ++jj)
            cc = fmaf(__builtin_amdgcn_exp2f(U + Crow[jj] + vv[jj]), Crow[jj], cc);
        #pragma unroll
        for (int m = 1; m < 64; m <<= 1) cc += __shfl_xor(cc, m);
        if (t == 0)
            cost_all[(size_t)(MAX_ITER - 1) * (2 * nE) + b] = -EPS_LN2 * cc;
    }
}

// ---------------- err reduction: 20 blocks, deterministic ----------------
__global__ __launch_bounds__(256) void err_reduce(
    const float* __restrict__ err_part, float* __restrict__ err_mean, int nE)
{
    int side = blockIdx.x / MAX_ITER;
    int it = blockIdx.x - side * MAX_ITER;
    const float* p = err_part + (size_t)it * (2 * nE) + side * nE;
    float s = 0.f;
    for (int idx = threadIdx.x; idx < nE; idx += 256) s += p[idx];
    __shared__ float red[256];
    red[threadIdx.x] = s;
    __syncthreads();
    for (int stride = 128; stride > 0; stride >>= 1) {
        if (threadIdx.x < stride) red[threadIdx.x] += red[threadIdx.x + stride];
        __syncthreads();
    }
    if (threadIdx.x == 0) err_mean[side * MAX_ITER + it] = red[0] / (float)nE;
}

// ---------------- final: pick T per side, gather costs, reduce loss -------
__global__ __launch_bounds__(256) void final_loss(
    const float* __restrict__ err_mean, const float* __restrict__ cost_all,
    float* __restrict__ out, int nE)
{
    int Tp = MAX_ITER, Tn = MAX_ITER;
    for (int it = 0; it < MAX_ITER; ++it)
        if (err_mean[it] < THRESH) { Tp = it + 1; break; }
    for (int it = 0; it < MAX_ITER; ++it)
        if (err_mean[MAX_ITER + it] < THRESH) { Tn = it + 1; break; }

    float s = 0.f;
    for (int b = threadIdx.x; b < 2 * nE; b += 256) {
        int side = (b >= nE) ? 1 : 0;
        int T = side ? Tn : Tp;
        float cost = cost_all[(size_t)(T - 1) * (2 * nE) + b];
        s += side ? expf(-cost) : cost * cost;
    }
    __shared__ float red[256];
    red[threadIdx.x] = s;
    __syncthreads();
    for (int stride = 128; stride > 0; stride >>= 1) {
        if (threadIdx.x < stride) red[threadIdx.x] += red[threadIdx.x + stride];
        __syncthreads();
    }
    if (threadIdx.x == 0) out[0] = red[0] / (float)nE;
}

extern "C" void kernel_launch(void* const* d_in, const int* in_sizes, int n_in,
                              void* d_out, int out_size, void* d_ws, size_t ws_size,
                              hipStream_t stream)
{
    const float* X = (const float*)d_in[0];
    const float* W = (const float*)d_in[1];
    const int* ep = (const int*)d_in[2];
    const int* en = (const int*)d_in[3];
    float* out = (float*)d_out;

    int K = in_sizes[1] / EMB;     // 256
    int M = in_sizes[0] / K;       // 10000
    int nE = in_sizes[2] / 2;      // 4096
    int MK = M * K;
    int total = MK + K * EMB;

    float* ws = (float*)d_ws;
    float* Z = ws;                                              // M*EMB f32
    float* after_Z = Z + (size_t)M * EMB;
    _Float16* Xh = (_Float16*)after_Z;                          // MK f16
    _Float16* WhT = Xh + (size_t)MK;                            // K*EMB f16
    float* err_part = (float*)(WhT + (size_t)K * EMB);          // MAX_ITER*2nE
    float* cost_all = err_part + (size_t)MAX_ITER * 2 * nE;     // MAX_ITER*2nE
    float* err_mean = cost_all + (size_t)MAX_ITER * 2 * nE;     // 32 (20 used)

    convert_f16<<<(total + 255) / 256, 256, 0, stream>>>(X, W, Xh, WhT, MK, K, EMB, total);

    dim3 gg((M + 63) / 64, EMB / 64);
    gemm_mfma_f16<<<gg, 256, 0, stream>>>(Xh, WhT, Z, M, K, EMB);

    int nblk = (2 * nE) / WPB;
    sinkhorn_fused<<<nblk, 64 * WPB, 0, stream>>>(Z, ep, en, nE, err_part, cost_all);
    err_reduce<<<2 * MAX_ITER, 256, 0, stream>>>(err_part, err_mean, nE);
    final_loss<<<1, 256, 0, stream>>>(err_mean, cost_all, out, nE);
}

// Round 5
// 146.451 us; speedup vs baseline: 1.3121x; 1.0902x over previous
//
#include <hip/hip_runtime.h>
#include <hip/hip_bf16.h>
#include <math.h>

#define N_POINTS 32
#define SPACE_DIM 16
#define EMB 512
#define THRESH 0.1f
#define MAX_ITER 10

// log2-domain constants
#define NEG10LOG2E -14.42695040888963f   // -10*log2(e): C -> Crow2
#define EPS_LN2     0.0693147180559945f  // eps*ln2
#define LOGMU2     -4.99999953834f       // log2(1/32 + 1e-8)

typedef _Float16 half8 __attribute__((ext_vector_type(8)));
typedef _Float16 half4 __attribute__((ext_vector_type(4)));
typedef float floatx4 __attribute__((ext_vector_type(4)));

#define BSTRIDE 264   // halves; 528 B = 33*16 -> b128-aligned rows, conflict-free frags

// ---------------- Fused GEMM: Z = X @ W (fp32 in, f16 MFMA, fp32 out) -------
// Per-block: stage 256x64 W-tile transposed+converted into LDS; A-fragments
// converted from fp32 in registers. Also zeroes the err_final counter.
__global__ __launch_bounds__(256) void gemm_fused(
    const float* __restrict__ X, const float* __restrict__ W,
    float* __restrict__ Z, int M, int K, int N, unsigned* __restrict__ counter)
{
    if (blockIdx.x == 0 && blockIdx.y == 0 && threadIdx.x == 0) counter[0] = 0u;

    __shared__ _Float16 Bs[64][BSTRIDE];   // [n][k]

    int t = threadIdx.x;
    int n0 = blockIdx.y * 64;

    // ---- stage W-tile (256k x 64n fp32) -> Bs[n][k] f16, 4x4 sub-blocks ----
    #pragma unroll
    for (int s = 0; s < 4; ++s) {
        int u = s * 256 + t;
        int nb = u & 15;          // n-group (4 cols)
        int kb = u >> 4;          // k-group (4 rows)
        float4 r0v = *(const float4*)&W[(size_t)(kb * 4 + 0) * N + n0 + nb * 4];
        float4 r1v = *(const float4*)&W[(size_t)(kb * 4 + 1) * N + n0 + nb * 4];
        float4 r2v = *(const float4*)&W[(size_t)(kb * 4 + 2) * N + n0 + nb * 4];
        float4 r3v = *(const float4*)&W[(size_t)(kb * 4 + 3) * N + n0 + nb * 4];
        float c0[4] = {r0v.x, r0v.y, r0v.z, r0v.w};
        float c1[4] = {r1v.x, r1v.y, r1v.z, r1v.w};
        float c2[4] = {r2v.x, r2v.y, r2v.z, r2v.w};
        float c3[4] = {r3v.x, r3v.y, r3v.z, r3v.w};
        #pragma unroll
        for (int c = 0; c < 4; ++c) {
            half4 h = {(_Float16)c0[c], (_Float16)c1[c],
                       (_Float16)c2[c], (_Float16)c3[c]};
            *(half4*)&Bs[nb * 4 + c][kb * 4] = h;
        }
    }
    __syncthreads();

    int wave = t >> 6;
    int lane = t & 63;
    int quad = lane >> 4;
    int l16 = lane & 15;

    int mrow = blockIdx.x * 64 + wave * 16 + l16;
    int msafe = mrow < M ? mrow : M - 1;
    const float4* xp = (const float4*)(X + (size_t)msafe * K);

    floatx4 acc[4] = {{0.f,0.f,0.f,0.f},{0.f,0.f,0.f,0.f},
                      {0.f,0.f,0.f,0.f},{0.f,0.f,0.f,0.f}};

    for (int k0 = 0; k0 < K; k0 += 32) {
        float4 lo = xp[(k0 >> 2) + quad * 2];
        float4 hi = xp[(k0 >> 2) + quad * 2 + 1];
        half8 a = {(_Float16)lo.x, (_Float16)lo.y, (_Float16)lo.z, (_Float16)lo.w,
                   (_Float16)hi.x, (_Float16)hi.y, (_Float16)hi.z, (_Float16)hi.w};
        #pragma unroll
        for (int ct = 0; ct < 4; ++ct) {
            half8 b = *(const half8*)&Bs[ct * 16 + l16][k0 + quad * 8];
            acc[ct] = __builtin_amdgcn_mfma_f32_16x16x32_f16(a, b, acc[ct], 0, 0, 0);
        }
    }

    int rbase = blockIdx.x * 64 + wave * 16 + quad * 4;
    #pragma unroll
    for (int ct = 0; ct < 4; ++ct) {
        int col = n0 + ct * 16 + l16;
        #pragma unroll
        for (int r = 0; r < 4; ++r) {
            int row = rbase + r;
            if (row < M) Z[(size_t)row * N + col] = acc[ct][r];
        }
    }
}

// ---------------- Fused Sinkhorn: 4 edges/block, 1 wave/edge, log2 domain ---
#define WPB 4

__global__ __launch_bounds__(256, 4) void sinkhorn_fused(
    const float* __restrict__ Z,
    const int* __restrict__ ep, const int* __restrict__ en,
    int nE,
    float* __restrict__ err_part,   // [MAX_ITER][2nE]
    float* __restrict__ cost_all)   // [MAX_ITER][2nE]
{
    __shared__ float shm[WPB][32 * 36];  // union: sb = 32x20, csh = 32x36
    __shared__ float uvs[WPB][64];       // U2[0:32], V2[32:64]

    int tid = threadIdx.x;
    int wv = tid >> 6;
    int t = tid & 63;
    int b = blockIdx.x * WPB + wv;

    int side = (b >= nE) ? 1 : 0;
    int e = b - side * nE;
    const int* edges = side ? en : ep;
    int nx = edges[e];
    int ny = edges[e + nE];

    int c = t & 31;
    int h = t >> 5;
    int r0 = h * 16;

    float* sb  = shm[wv];
    float* csh = shm[wv];
    float* Ul  = uvs[wv];
    float* Vl  = uvs[wv] + 32;

    // stage b point rows into LDS, padded stride 20
    {
        const float4* zb4 = (const float4*)(Z + (size_t)ny * EMB);
        float4 q0 = zb4[t * 2];
        float4 q1 = zb4[t * 2 + 1];
        float* dst = sb + (t >> 1) * 20 + (t & 1) * 8;
        ((float4*)dst)[0] = q0;
        ((float4*)dst)[1] = q1;
    }
    // own a-row in registers
    float areg[16];
    {
        const float4* za4 = (const float4*)(Z + (size_t)nx * EMB + c * SPACE_DIM);
        float4 a0 = za4[0], a1 = za4[1], a2 = za4[2], a3 = za4[3];
        areg[0]=a0.x; areg[1]=a0.y; areg[2]=a0.z; areg[3]=a0.w;
        areg[4]=a1.x; areg[5]=a1.y; areg[6]=a1.z; areg[7]=a1.w;
        areg[8]=a2.x; areg[9]=a2.y; areg[10]=a2.z; areg[11]=a2.w;
        areg[12]=a3.x; areg[13]=a3.y; areg[14]=a3.z; areg[15]=a3.w;
    }

    // Crow[jj] = -10*log2e * ||a_c - b_{r0+jj}||^2
    float Crow[16];
    #pragma unroll
    for (int jj = 0; jj < 16; ++jj) {
        const float* bp = sb + (r0 + jj) * 20;
        float s = 0.f;
        #pragma unroll
        for (int d = 0; d < SPACE_DIM; ++d) {
            float diff = areg[d] - bp[d];
            s = fmaf(diff, diff, s);
        }
        Crow[jj] = s * NEG10LOG2E;
    }
    // transpose through LDS (stride 36) to get column fragment
    #pragma unroll
    for (int g = 0; g < 4; ++g) {
        *(float4*)&csh[c * 36 + r0 + g * 4] =
            make_float4(Crow[g*4+0], Crow[g*4+1], Crow[g*4+2], Crow[g*4+3]);
    }
    float Ccol[16];
    #pragma unroll
    for (int ii = 0; ii < 16; ++ii)
        Ccol[ii] = csh[(r0 + ii) * 36 + c];

    Vl[c] = 0.f;
    float U = 0.f;

    for (int it = 0; it < MAX_ITER; ++it) {
        // ---- row pass ----
        float w[16];
        {
            const float4* vp = (const float4*)(Vl + r0);
            float4 v0 = vp[0], v1 = vp[1], v2 = vp[2], v3 = vp[3];
            float vv[16] = {v0.x,v0.y,v0.z,v0.w, v1.x,v1.y,v1.z,v1.w,
                            v2.x,v2.y,v2.z,v2.w, v3.x,v3.y,v3.z,v3.w};
            #pragma unroll
            for (int jj = 0; jj < 16; ++jj) w[jj] = Crow[jj] + vv[jj];
        }
        float mx = w[0];
        #pragma unroll
        for (int jj = 1; jj < 16; ++jj) mx = fmaxf(mx, w[jj]);
        mx = fmaxf(mx, __shfl_xor(mx, 32));
        float sm = 0.f, pc = 0.f;
        #pragma unroll
        for (int jj = 0; jj < 16; ++jj) {
            float ex = __builtin_amdgcn_exp2f(w[jj] - mx);
            sm += ex;
            pc = fmaf(ex, Crow[jj], pc);   // cost partial reusing the exps
        }
        sm += __shfl_xor(sm, 32);

        if (it > 0) {
            float cc = __builtin_amdgcn_exp2f(U + mx) * pc;
            #pragma unroll
            for (int m = 1; m < 64; m <<= 1) cc += __shfl_xor(cc, m);
            if (t == 0)
                cost_all[(size_t)(it - 1) * (2 * nE) + b] = -EPS_LN2 * cc;
        }

        float Un = LOGMU2 - (mx + __builtin_amdgcn_logf(sm));
        float du = fabsf(Un - U);
        #pragma unroll
        for (int m = 1; m < 32; m <<= 1) du += __shfl_xor(du, m);
        if (t == 0) err_part[(size_t)it * (2 * nE) + b] = EPS_LN2 * du;
        U = Un;
        Ul[c] = U;

        // ---- col pass ----
        float wc[16];
        {
            const float4* up = (const float4*)(Ul + r0);
            float4 u0 = up[0], u1 = up[1], u2 = up[2], u3 = up[3];
            float uu[16] = {u0.x,u0.y,u0.z,u0.w, u1.x,u1.y,u1.z,u1.w,
                            u2.x,u2.y,u2.z,u2.w, u3.x,u3.y,u3.z,u3.w};
            #pragma unroll
            for (int ii = 0; ii < 16; ++ii) wc[ii] = Ccol[ii] + uu[ii];
        }
        float mx2 = wc[0];
        #pragma unroll
        for (int ii = 1; ii < 16; ++ii) mx2 = fmaxf(mx2, wc[ii]);
        mx2 = fmaxf(mx2, __shfl_xor(mx2, 32));
        float sm2 = 0.f;
        #pragma unroll
        for (int ii = 0; ii < 16; ++ii) sm2 += __builtin_amdgcn_exp2f(wc[ii] - mx2);
        sm2 += __shfl_xor(sm2, 32);
        float Vn = LOGMU2 - (mx2 + __builtin_amdgcn_logf(sm2));
        Vl[c] = Vn;
    }

    // final-state cost -> index MAX_ITER-1
    {
        const float4* vp = (const float4*)(Vl + r0);
        float4 v0 = vp[0], v1 = vp[1], v2 = vp[2], v3 = vp[3];
        float vv[16] = {v0.x,v0.y,v0.z,v0.w, v1.x,v1.y,v1.z,v1.w,
                        v2.x,v2.y,v2.z,v2.w, v3.x,v3.y,v3.z,v3.w};
        float cc = 0.f;
        #pragma unroll
        for (int jj = 0; jj < 16; ++jj)
            cc = fmaf(__builtin_amdgcn_exp2f(U + Crow[jj] + vv[jj]), Crow[jj], cc);
        #pragma unroll
        for (int m = 1; m < 64; m <<= 1) cc += __shfl_xor(cc, m);
        if (t == 0)
            cost_all[(size_t)(MAX_ITER - 1) * (2 * nE) + b] = -EPS_LN2 * cc;
    }
}

// ---------------- err reduce + final loss, last-block pattern ----------------
__global__ __launch_bounds__(256) void err_final(
    const float* __restrict__ err_part, const float* __restrict__ cost_all,
    float* __restrict__ err_mean, unsigned* __restrict__ counter,
    float* __restrict__ out, int nE)
{
    __shared__ float red[256];
    __shared__ int is_last;

    int side = blockIdx.x / MAX_ITER;
    int it = blockIdx.x - side * MAX_ITER;
    const float* p = err_part + (size_t)it * (2 * nE) + side * nE;
    float s = 0.f;
    for (int idx = threadIdx.x; idx < nE; idx += 256) s += p[idx];
    red[threadIdx.x] = s;
    __syncthreads();
    for (int stride = 128; stride > 0; stride >>= 1) {
        if (threadIdx.x < stride) red[threadIdx.x] += red[threadIdx.x + stride];
        __syncthreads();
    }
    if (threadIdx.x == 0) {
        __hip_atomic_store(&err_mean[side * MAX_ITER + it], red[0] / (float)nE,
                           __ATOMIC_RELAXED, __HIP_MEMORY_SCOPE_AGENT);
        __threadfence();
        unsigned old = __hip_atomic_fetch_add(counter, 1u, __ATOMIC_ACQ_REL,
                                              __HIP_MEMORY_SCOPE_AGENT);
        is_last = (old == 2 * MAX_ITER - 1);
    }
    __syncthreads();
    if (!is_last) return;

    // last block: all err_means are globally visible (agent-scope loads)
    float em[2 * MAX_ITER];
    #pragma unroll
    for (int i = 0; i < 2 * MAX_ITER; ++i)
        em[i] = __hip_atomic_load(&err_mean[i], __ATOMIC_RELAXED,
                                  __HIP_MEMORY_SCOPE_AGENT);
    int Tp = MAX_ITER, Tn = MAX_ITER;
    for (int i = 0; i < MAX_ITER; ++i)
        if (em[i] < THRESH) { Tp = i + 1; break; }
    for (int i = 0; i < MAX_ITER; ++i)
        if (em[MAX_ITER + i] < THRESH) { Tn = i + 1; break; }

    float acc = 0.f;
    for (int b = threadIdx.x; b < 2 * nE; b += 256) {
        int sd = (b >= nE) ? 1 : 0;
        int T = sd ? Tn : Tp;
        float cost = cost_all[(size_t)(T - 1) * (2 * nE) + b];
        acc += sd ? expf(-cost) : cost * cost;
    }
    __syncthreads();
    red[threadIdx.x] = acc;
    __syncthreads();
    for (int stride = 128; stride > 0; stride >>= 1) {
        if (threadIdx.x < stride) red[threadIdx.x] += red[threadIdx.x + stride];
        __syncthreads();
    }
    if (threadIdx.x == 0) out[0] = red[0] / (float)nE;
}

extern "C" void kernel_launch(void* const* d_in, const int* in_sizes, int n_in,
                              void* d_out, int out_size, void* d_ws, size_t ws_size,
                              hipStream_t stream)
{
    const float* X = (const float*)d_in[0];
    const float* W = (const float*)d_in[1];
    const int* ep = (const int*)d_in[2];
    const int* en = (const int*)d_in[3];
    float* out = (float*)d_out;

    int K = in_sizes[1] / EMB;     // 256
    int M = in_sizes[0] / K;       // 10000
    int nE = in_sizes[2] / 2;      // 4096

    float* ws = (float*)d_ws;
    float* Z = ws;                                              // M*EMB f32
    float* err_part = Z + (size_t)M * EMB;                      // MAX_ITER*2nE
    float* cost_all = err_part + (size_t)MAX_ITER * 2 * nE;     // MAX_ITER*2nE
    float* err_mean = cost_all + (size_t)MAX_ITER * 2 * nE;     // 32 (20 used)
    unsigned* counter = (unsigned*)(err_mean + 32);             // 1

    dim3 gg((M + 63) / 64, EMB / 64);
    gemm_fused<<<gg, 256, 0, stream>>>(X, W, Z, M, K, EMB, counter);

    int nblk = (2 * nE) / WPB;
    sinkhorn_fused<<<nblk, 64 * WPB, 0, stream>>>(Z, ep, en, nE, err_part, cost_all);

    err_final<<<2 * MAX_ITER, 256, 0, stream>>>(err_part, cost_all, err_mean,
                                                counter, out, nE);
}